// Round 1
// baseline (531.642 us; speedup 1.0000x reference)
//
#include <hip/hip_runtime.h>

#define NDIM 128

// ---------------- per-node attention projections: s_k = h.Wa_k[0:128], d_k = h.Wa_k[128:256]
__global__ void k_proj(const float* __restrict__ h,
                       const float* __restrict__ Wa1,
                       const float* __restrict__ Wa2,
                       const float* __restrict__ Wa3,
                       float* __restrict__ proj, int N)
{
    int lane = threadIdx.x & 63;
    int wid  = blockIdx.x * (blockDim.x >> 6) + (threadIdx.x >> 6);
    int nw   = gridDim.x * (blockDim.x >> 6);
    float w1s0 = Wa1[lane], w1s1 = Wa1[64 + lane], w1d0 = Wa1[128 + lane], w1d1 = Wa1[192 + lane];
    float w2s0 = Wa2[lane], w2s1 = Wa2[64 + lane], w2d0 = Wa2[128 + lane], w2d1 = Wa2[192 + lane];
    float w3s0 = Wa3[lane], w3s1 = Wa3[64 + lane], w3d0 = Wa3[128 + lane], w3d1 = Wa3[192 + lane];
    for (int n = wid; n < N; n += nw) {
        float h0 = h[(size_t)n * NDIM + lane];
        float h1 = h[(size_t)n * NDIM + 64 + lane];
        float s1 = h0 * w1s0 + h1 * w1s1;
        float s2 = h0 * w2s0 + h1 * w2s1;
        float s3 = h0 * w3s0 + h1 * w3s1;
        float d1 = h0 * w1d0 + h1 * w1d1;
        float d2 = h0 * w2d0 + h1 * w2d1;
        float d3 = h0 * w3d0 + h1 * w3d1;
#pragma unroll
        for (int m = 1; m < 64; m <<= 1) {
            s1 += __shfl_xor(s1, m);
            s2 += __shfl_xor(s2, m);
            s3 += __shfl_xor(s3, m);
            d1 += __shfl_xor(d1, m);
            d2 += __shfl_xor(d2, m);
            d3 += __shfl_xor(d3, m);
        }
        if (lane == 0) {
            *(float4*)(proj + (size_t)n * 8)     = make_float4(s1, s2, s3, 0.f);
            *(float4*)(proj + (size_t)n * 8 + 4) = make_float4(d1, d2, d3, 0.f);
        }
    }
}

// ---------------- dst histogram
__global__ void k_hist(const int* __restrict__ dst, int* __restrict__ cnt, int E)
{
    int i = blockIdx.x * blockDim.x + threadIdx.x;
    if (i < E) atomicAdd(&cnt[dst[i]], 1);
}

// ---------------- hierarchical exclusive scan (chunk 512)
__global__ void k_scan1(const int* __restrict__ cnt, int* __restrict__ offs,
                        int* __restrict__ bsums, int N)
{
    __shared__ int s[512];
    int i = blockIdx.x * 512 + threadIdx.x;
    int v = (i < N) ? cnt[i] : 0;
    s[threadIdx.x] = v;
    __syncthreads();
    for (int d = 1; d < 512; d <<= 1) {
        int t = (threadIdx.x >= d) ? s[threadIdx.x - d] : 0;
        __syncthreads();
        s[threadIdx.x] += t;
        __syncthreads();
    }
    if (i < N) offs[i] = s[threadIdx.x] - v;
    if (threadIdx.x == 511) bsums[blockIdx.x] = s[511];
}

__global__ void k_scan2(int* __restrict__ bsums, int nb)
{
    __shared__ int s[128];
    int t = threadIdx.x;
    int v = (t < nb) ? bsums[t] : 0;
    s[t] = v;
    __syncthreads();
    for (int d = 1; d < 128; d <<= 1) {
        int u = (t >= d) ? s[t - d] : 0;
        __syncthreads();
        s[t] += u;
        __syncthreads();
    }
    if (t < nb) bsums[t] = s[t] - v;  // exclusive
}

__global__ void k_scan3(int* __restrict__ offs, const int* __restrict__ bsums,
                        int* __restrict__ cursor, int N, int E)
{
    int i = blockIdx.x * 512 + threadIdx.x;
    if (i < N) {
        int o = offs[i] + bsums[blockIdx.x];
        offs[i]   = o;
        cursor[i] = o;
    }
    if (i == 0) offs[N] = E;
}

// ---------------- per-edge: attention numerators -> att sums (atomic), CSR scatter of src
__global__ void k_edge(const int* __restrict__ src, const int* __restrict__ dst,
                       const float* __restrict__ proj,
                       const float* __restrict__ ba1, const float* __restrict__ ba2,
                       const float* __restrict__ ba3,
                       float* __restrict__ att, int* __restrict__ cursor,
                       int* __restrict__ perm, int E)
{
    int e = blockIdx.x * blockDim.x + threadIdx.x;
    if (e >= E) return;
    int s = src[e];
    int d = dst[e];
    float4 sp = *(const float4*)(proj + (size_t)s * 8);
    float4 dp = *(const float4*)(proj + (size_t)d * 8 + 4);
    float b1 = ba1[0], b2 = ba2[0], b3 = ba3[0];
    float a1 = __expf(fmaxf(sp.x + dp.x + b1, 0.f));
    float a2 = __expf(fmaxf(sp.y + dp.y + b2, 0.f));
    float a3 = __expf(fmaxf(sp.z + dp.z + b3, 0.f));
    atomicAdd(&att[(size_t)d * 4 + 0], a1);
    atomicAdd(&att[(size_t)d * 4 + 1], a2);
    atomicAdd(&att[(size_t)d * 4 + 2], a3);
    int pos = atomicAdd(&cursor[d], 1);
    perm[pos] = s;
}

// ---------------- per-dst-node aggregation: h_neigh = (1/deg) * sum avg_a * msg[src]
__global__ __launch_bounds__(128) void k_aggr(const float* __restrict__ msg,
                                              const float* __restrict__ proj,
                                              const float* __restrict__ att,
                                              const int* __restrict__ offs,
                                              const int* __restrict__ perm,
                                              const float* __restrict__ ba1,
                                              const float* __restrict__ ba2,
                                              const float* __restrict__ ba3,
                                              float* __restrict__ hneigh, int N)
{
    int n   = blockIdx.x;
    int tid = threadIdx.x;
    int o0 = offs[n], o1 = offs[n + 1];
    int deg = o1 - o0;
    if (deg == 0) {
        hneigh[(size_t)n * NDIM + tid] = 0.f;
        return;
    }
    float r1 = 1.f / att[(size_t)n * 4 + 0];
    float r2 = 1.f / att[(size_t)n * 4 + 1];
    float r3 = 1.f / att[(size_t)n * 4 + 2];
    float dd1 = proj[(size_t)n * 8 + 4];
    float dd2 = proj[(size_t)n * 8 + 5];
    float dd3 = proj[(size_t)n * 8 + 6];
    float b1 = ba1[0], b2 = ba2[0], b3 = ba3[0];
    __shared__ int   ssrc[128];
    __shared__ float sw[128];
    float acc = 0.f;
    for (int base = o0; base < o1; base += 128) {
        int m = min(128, o1 - base);
        if (tid < m) {
            int s = perm[base + tid];
            float4 sp = *(const float4*)(proj + (size_t)s * 8);
            float a1 = __expf(fmaxf(sp.x + dd1 + b1, 0.f));
            float a2 = __expf(fmaxf(sp.y + dd2 + b2, 0.f));
            float a3 = __expf(fmaxf(sp.z + dd3 + b3, 0.f));
            sw[tid]   = (a1 * r1 + a2 * r2 + a3 * r3) * (1.f / 3.f);
            ssrc[tid] = s;
        }
        __syncthreads();
#pragma unroll 4
        for (int j = 0; j < m; ++j)
            acc += sw[j] * msg[(size_t)ssrc[j] * NDIM + tid];
        __syncthreads();
    }
    hneigh[(size_t)n * NDIM + tid] = acc * (1.f / (float)deg);
}

// ---------------- fp32 GEMM: out[N,128] = act( A0@W0 (+ A1@W1) + bias ), K=128
// tile 64 rows x 64 cols, 256 threads, 4x4 micro-tile, A and W staged in LDS
#define GBM 64
#define GBN 64
__global__ __launch_bounds__(256) void k_gemm(const float* __restrict__ A0,
                                              const float* __restrict__ A1,
                                              const float* __restrict__ W0,
                                              const float* __restrict__ W1,
                                              const float* __restrict__ bias,
                                              float* __restrict__ out,
                                              int N, int doRelu)
{
    __shared__ float As[GBM * 128];
    __shared__ float Ws[128 * GBN];
    int tid  = threadIdx.x;
    int row0 = blockIdx.x * GBM;
    int col0 = blockIdx.y * GBN;
    int tx = tid & 15, ty = tid >> 4;
    float acc[4][4] = {};
    int npass = (A1 != nullptr) ? 2 : 1;
    for (int p = 0; p < npass; ++p) {
        const float* A = p ? A1 : A0;
        const float* W = p ? W1 : W0;
        if (p) __syncthreads();  // protect LDS reuse across passes
        // stage A tile: 64x128 floats (coalesced float4)
#pragma unroll
        for (int j = 0; j < 8; ++j) {
            int id = tid + 256 * j;      // 0..2047 float4s
            int r  = id >> 5;
            int k4 = id & 31;
            int gr = row0 + r;
            float4 v = make_float4(0.f, 0.f, 0.f, 0.f);
            if (gr < N) v = *(const float4*)(A + (size_t)gr * 128 + k4 * 4);
            *(float4*)(As + r * 128 + k4 * 4) = v;
        }
        // stage W tile: 128x64 floats
#pragma unroll
        for (int j = 0; j < 8; ++j) {
            int id = tid + 256 * j;      // 0..2047 float4s
            int k  = id >> 4;
            int c4 = id & 15;
            *(float4*)(Ws + k * GBN + c4 * 4) =
                *(const float4*)(W + (size_t)k * 128 + col0 + c4 * 4);
        }
        __syncthreads();
#pragma unroll 4
        for (int k0 = 0; k0 < 128; k0 += 4) {
            float4 b0 = *(const float4*)(Ws + (k0 + 0) * GBN + tx * 4);
            float4 b1 = *(const float4*)(Ws + (k0 + 1) * GBN + tx * 4);
            float4 b2 = *(const float4*)(Ws + (k0 + 2) * GBN + tx * 4);
            float4 b3 = *(const float4*)(Ws + (k0 + 3) * GBN + tx * 4);
#pragma unroll
            for (int r = 0; r < 4; ++r) {
                float4 a = *(const float4*)(As + (ty * 4 + r) * 128 + k0);
                acc[r][0] += a.x * b0.x; acc[r][0] += a.y * b1.x; acc[r][0] += a.z * b2.x; acc[r][0] += a.w * b3.x;
                acc[r][1] += a.x * b0.y; acc[r][1] += a.y * b1.y; acc[r][1] += a.z * b2.y; acc[r][1] += a.w * b3.y;
                acc[r][2] += a.x * b0.z; acc[r][2] += a.y * b1.z; acc[r][2] += a.z * b2.z; acc[r][2] += a.w * b3.z;
                acc[r][3] += a.x * b0.w; acc[r][3] += a.y * b1.w; acc[r][3] += a.z * b2.w; acc[r][3] += a.w * b3.w;
            }
        }
    }
    float4 bv = *(const float4*)(bias + col0 + tx * 4);
#pragma unroll
    for (int r = 0; r < 4; ++r) {
        int gr = row0 + ty * 4 + r;
        if (gr < N) {
            float4 o;
            o.x = acc[r][0] + bv.x;
            o.y = acc[r][1] + bv.y;
            o.z = acc[r][2] + bv.z;
            o.w = acc[r][3] + bv.w;
            if (doRelu) {
                o.x = fmaxf(o.x, 0.f); o.y = fmaxf(o.y, 0.f);
                o.z = fmaxf(o.z, 0.f); o.w = fmaxf(o.w, 0.f);
            }
            *(float4*)(out + (size_t)gr * 128 + col0 + tx * 4) = o;
        }
    }
}

extern "C" void kernel_launch(void* const* d_in, const int* in_sizes, int n_in,
                              void* d_out, int out_size, void* d_ws, size_t ws_size,
                              hipStream_t stream)
{
    const float* h   = (const float*)d_in[0];
    const int*   src = (const int*)d_in[1];
    const int*   dst = (const int*)d_in[2];
    const float* Wm1 = (const float*)d_in[3];
    const float* bm1 = (const float*)d_in[4];
    const float* Wm2 = (const float*)d_in[5];
    const float* bm2 = (const float*)d_in[6];
    const float* Wm3 = (const float*)d_in[7];
    const float* bm3 = (const float*)d_in[8];
    const float* Wa1 = (const float*)d_in[9];
    const float* ba1 = (const float*)d_in[10];
    const float* Wa2 = (const float*)d_in[11];
    const float* ba2 = (const float*)d_in[12];
    const float* Wa3 = (const float*)d_in[13];
    const float* ba3 = (const float*)d_in[14];
    const float* Wc1 = (const float*)d_in[15];
    const float* bc1 = (const float*)d_in[16];
    const float* Wc2 = (const float*)d_in[17];
    const float* bc2 = (const float*)d_in[18];

    const int N = in_sizes[0] / NDIM;
    const int E = in_sizes[1];
    float* out = (float*)d_out;

    // workspace layout
    float* bufA = (float*)d_ws;                    // N*128
    float* bufB = bufA + (size_t)N * NDIM;         // N*128
    float* proj = bufB + (size_t)N * NDIM;         // N*8
    float* att  = proj + (size_t)N * 8;            // N*4
    int* cnt    = (int*)(att + (size_t)N * 4);     // N
    int* offs   = cnt + N;                         // N+1
    int* cursor = offs + N + 1;                    // N
    int* bsums  = cursor + N;                      // 128
    int* perm   = bsums + 128;                     // E

    hipMemsetAsync(cnt, 0, (size_t)N * sizeof(int), stream);
    hipMemsetAsync(att, 0, (size_t)N * 4 * sizeof(float), stream);

    k_proj<<<256, 256, 0, stream>>>(h, Wa1, Wa2, Wa3, proj, N);
    k_hist<<<(E + 255) / 256, 256, 0, stream>>>(dst, cnt, E);

    int nb = (N + 511) / 512;
    k_scan1<<<nb, 512, 0, stream>>>(cnt, offs, bsums, N);
    k_scan2<<<1, 128, 0, stream>>>(bsums, nb);
    k_scan3<<<nb, 512, 0, stream>>>(offs, bsums, cursor, N, E);

    k_edge<<<(E + 255) / 256, 256, 0, stream>>>(src, dst, proj, ba1, ba2, ba3,
                                                att, cursor, perm, E);

    dim3 ggrid((N + GBM - 1) / GBM, 128 / GBN);
    // 3-layer message MLP in node domain (msg ends in bufA)
    k_gemm<<<ggrid, 256, 0, stream>>>(h,    nullptr, Wm1, nullptr, bm1, bufA, N, 1);
    k_gemm<<<ggrid, 256, 0, stream>>>(bufA, nullptr, Wm2, nullptr, bm2, bufB, N, 1);
    k_gemm<<<ggrid, 256, 0, stream>>>(bufB, nullptr, Wm3, nullptr, bm3, bufA, N, 1);

    // aggregation: hneigh in bufB (reads msg=bufA)
    k_aggr<<<N, 128, 0, stream>>>(bufA, proj, att, offs, perm, ba1, ba2, ba3, bufB, N);

    // out = relu(h@Wc1[:128] + hneigh@Wc1[128:] + bc1) @ Wc2 + bc2
    k_gemm<<<ggrid, 256, 0, stream>>>(h, bufB, Wc1, Wc1 + 128 * 128, bc1, bufA, N, 1);
    k_gemm<<<ggrid, 256, 0, stream>>>(bufA, nullptr, Wc2, nullptr, bc2, out, N, 0);
}

// Round 2
// 416.247 us; speedup vs baseline: 1.2772x; 1.2772x over previous
//
#include <hip/hip_runtime.h>

#define NDIM 128

// ---------------- per-node attention projections: s_k = h.Wa_k[0:128], d_k = h.Wa_k[128:256]
__global__ void k_proj(const float* __restrict__ h,
                       const float* __restrict__ Wa1,
                       const float* __restrict__ Wa2,
                       const float* __restrict__ Wa3,
                       float* __restrict__ proj, int N)
{
    int lane = threadIdx.x & 63;
    int wid  = blockIdx.x * (blockDim.x >> 6) + (threadIdx.x >> 6);
    int nw   = gridDim.x * (blockDim.x >> 6);
    float w1s0 = Wa1[lane], w1s1 = Wa1[64 + lane], w1d0 = Wa1[128 + lane], w1d1 = Wa1[192 + lane];
    float w2s0 = Wa2[lane], w2s1 = Wa2[64 + lane], w2d0 = Wa2[128 + lane], w2d1 = Wa2[192 + lane];
    float w3s0 = Wa3[lane], w3s1 = Wa3[64 + lane], w3d0 = Wa3[128 + lane], w3d1 = Wa3[192 + lane];
    for (int n = wid; n < N; n += nw) {
        float h0 = h[(size_t)n * NDIM + lane];
        float h1 = h[(size_t)n * NDIM + 64 + lane];
        float s1 = h0 * w1s0 + h1 * w1s1;
        float s2 = h0 * w2s0 + h1 * w2s1;
        float s3 = h0 * w3s0 + h1 * w3s1;
        float d1 = h0 * w1d0 + h1 * w1d1;
        float d2 = h0 * w2d0 + h1 * w2d1;
        float d3 = h0 * w3d0 + h1 * w3d1;
#pragma unroll
        for (int m = 1; m < 64; m <<= 1) {
            s1 += __shfl_xor(s1, m);
            s2 += __shfl_xor(s2, m);
            s3 += __shfl_xor(s3, m);
            d1 += __shfl_xor(d1, m);
            d2 += __shfl_xor(d2, m);
            d3 += __shfl_xor(d3, m);
        }
        if (lane == 0) {
            *(float4*)(proj + (size_t)n * 8)     = make_float4(s1, s2, s3, 0.f);
            *(float4*)(proj + (size_t)n * 8 + 4) = make_float4(d1, d2, d3, 0.f);
        }
    }
}

// ---------------- dst histogram
__global__ void k_hist(const int* __restrict__ dst, int* __restrict__ cnt, int E)
{
    int i = blockIdx.x * blockDim.x + threadIdx.x;
    if (i < E) atomicAdd(&cnt[dst[i]], 1);
}

// ---------------- hierarchical exclusive scan (chunk 512)
__global__ void k_scan1(const int* __restrict__ cnt, int* __restrict__ offs,
                        int* __restrict__ bsums, int N)
{
    __shared__ int s[512];
    int i = blockIdx.x * 512 + threadIdx.x;
    int v = (i < N) ? cnt[i] : 0;
    s[threadIdx.x] = v;
    __syncthreads();
    for (int d = 1; d < 512; d <<= 1) {
        int t = (threadIdx.x >= d) ? s[threadIdx.x - d] : 0;
        __syncthreads();
        s[threadIdx.x] += t;
        __syncthreads();
    }
    if (i < N) offs[i] = s[threadIdx.x] - v;
    if (threadIdx.x == 511) bsums[blockIdx.x] = s[511];
}

__global__ void k_scan2(int* __restrict__ bsums, int nb)
{
    __shared__ int s[128];
    int t = threadIdx.x;
    int v = (t < nb) ? bsums[t] : 0;
    s[t] = v;
    __syncthreads();
    for (int d = 1; d < 128; d <<= 1) {
        int u = (t >= d) ? s[t - d] : 0;
        __syncthreads();
        s[t] += u;
        __syncthreads();
    }
    if (t < nb) bsums[t] = s[t] - v;  // exclusive
}

__global__ void k_scan3(int* __restrict__ offs, const int* __restrict__ bsums,
                        int* __restrict__ cursor, int N, int E)
{
    int i = blockIdx.x * 512 + threadIdx.x;
    if (i < N) {
        int o = offs[i] + bsums[blockIdx.x];
        offs[i]   = o;
        cursor[i] = o;
    }
    if (i == 0) offs[N] = E;
}

// ---------------- minimal CSR build: scatter src ids into dst-grouped segments
__global__ void k_edge(const int* __restrict__ src, const int* __restrict__ dst,
                       int* __restrict__ cursor, int* __restrict__ perm, int E)
{
    int e = blockIdx.x * blockDim.x + threadIdx.x;
    if (e >= E) return;
    int d = dst[e];
    int pos = atomicAdd(&cursor[d], 1);
    perm[pos] = src[e];
}

// ---------------- per-dst-node aggregation (two-pass: att sums, then weighted msg sum)
__global__ __launch_bounds__(128) void k_aggr(const float* __restrict__ msg,
                                              const float* __restrict__ proj,
                                              const int* __restrict__ offs,
                                              const int* __restrict__ perm,
                                              const float* __restrict__ ba1,
                                              const float* __restrict__ ba2,
                                              const float* __restrict__ ba3,
                                              float* __restrict__ hneigh, int N)
{
    int n   = blockIdx.x;
    int tid = threadIdx.x;
    int o0 = offs[n], o1 = offs[n + 1];
    int deg = o1 - o0;
    if (deg == 0) {
        hneigh[(size_t)n * NDIM + tid] = 0.f;
        return;
    }
    float dd1 = proj[(size_t)n * 8 + 4];
    float dd2 = proj[(size_t)n * 8 + 5];
    float dd3 = proj[(size_t)n * 8 + 6];
    float b1 = ba1[0], b2 = ba2[0], b3 = ba3[0];

    // ---- pass 1: per-dst attention denominators
    float s1 = 0.f, s2 = 0.f, s3 = 0.f;
    for (int i = o0 + tid; i < o1; i += 128) {
        int s = perm[i];
        float4 sp = *(const float4*)(proj + (size_t)s * 8);
        s1 += __expf(fmaxf(sp.x + dd1 + b1, 0.f));
        s2 += __expf(fmaxf(sp.y + dd2 + b2, 0.f));
        s3 += __expf(fmaxf(sp.z + dd3 + b3, 0.f));
    }
#pragma unroll
    for (int m = 1; m < 64; m <<= 1) {
        s1 += __shfl_xor(s1, m);
        s2 += __shfl_xor(s2, m);
        s3 += __shfl_xor(s3, m);
    }
    __shared__ float red[2][3];
    if ((tid & 63) == 0) {
        int w = tid >> 6;
        red[w][0] = s1; red[w][1] = s2; red[w][2] = s3;
    }
    __syncthreads();
    float r1 = 1.f / (red[0][0] + red[1][0]);
    float r2 = 1.f / (red[0][1] + red[1][1]);
    float r3 = 1.f / (red[0][2] + red[1][2]);
    __syncthreads();

    // ---- pass 2: weighted message sum
    __shared__ int   ssrc[128];
    __shared__ float sw[128];
    float acc = 0.f;
    for (int base = o0; base < o1; base += 128) {
        int m = min(128, o1 - base);
        if (tid < m) {
            int s = perm[base + tid];
            float4 sp = *(const float4*)(proj + (size_t)s * 8);
            float a1 = __expf(fmaxf(sp.x + dd1 + b1, 0.f));
            float a2 = __expf(fmaxf(sp.y + dd2 + b2, 0.f));
            float a3 = __expf(fmaxf(sp.z + dd3 + b3, 0.f));
            sw[tid]   = (a1 * r1 + a2 * r2 + a3 * r3) * (1.f / 3.f);
            ssrc[tid] = s;
        }
        __syncthreads();
#pragma unroll 4
        for (int j = 0; j < m; ++j)
            acc += sw[j] * msg[(size_t)ssrc[j] * NDIM + tid];
        __syncthreads();
    }
    hneigh[(size_t)n * NDIM + tid] = acc * (1.f / (float)deg);
}

// ---------------- fp32 GEMM: out[N,128] = act( A0@W0 (+ A1@W1) + bias ), K=128
// tile 64 rows x 64 cols, 256 threads, 4x4 micro-tile, A and W staged in LDS
#define GBM 64
#define GBN 64
__global__ __launch_bounds__(256) void k_gemm(const float* __restrict__ A0,
                                              const float* __restrict__ A1,
                                              const float* __restrict__ W0,
                                              const float* __restrict__ W1,
                                              const float* __restrict__ bias,
                                              float* __restrict__ out,
                                              int N, int doRelu)
{
    __shared__ float As[GBM * 128];
    __shared__ float Ws[128 * GBN];
    int tid  = threadIdx.x;
    int row0 = blockIdx.x * GBM;
    int col0 = blockIdx.y * GBN;
    int tx = tid & 15, ty = tid >> 4;
    float acc[4][4] = {};
    int npass = (A1 != nullptr) ? 2 : 1;
    for (int p = 0; p < npass; ++p) {
        const float* A = p ? A1 : A0;
        const float* W = p ? W1 : W0;
        if (p) __syncthreads();  // protect LDS reuse across passes
        // stage A tile: 64x128 floats (coalesced float4)
#pragma unroll
        for (int j = 0; j < 8; ++j) {
            int id = tid + 256 * j;      // 0..2047 float4s
            int r  = id >> 5;
            int k4 = id & 31;
            int gr = row0 + r;
            float4 v = make_float4(0.f, 0.f, 0.f, 0.f);
            if (gr < N) v = *(const float4*)(A + (size_t)gr * 128 + k4 * 4);
            *(float4*)(As + r * 128 + k4 * 4) = v;
        }
        // stage W tile: 128x64 floats
#pragma unroll
        for (int j = 0; j < 8; ++j) {
            int id = tid + 256 * j;      // 0..2047 float4s
            int k  = id >> 4;
            int c4 = id & 15;
            *(float4*)(Ws + k * GBN + c4 * 4) =
                *(const float4*)(W + (size_t)k * 128 + col0 + c4 * 4);
        }
        __syncthreads();
#pragma unroll 4
        for (int k0 = 0; k0 < 128; k0 += 4) {
            float4 b0 = *(const float4*)(Ws + (k0 + 0) * GBN + tx * 4);
            float4 b1 = *(const float4*)(Ws + (k0 + 1) * GBN + tx * 4);
            float4 b2 = *(const float4*)(Ws + (k0 + 2) * GBN + tx * 4);
            float4 b3 = *(const float4*)(Ws + (k0 + 3) * GBN + tx * 4);
#pragma unroll
            for (int r = 0; r < 4; ++r) {
                float4 a = *(const float4*)(As + (ty * 4 + r) * 128 + k0);
                acc[r][0] += a.x * b0.x; acc[r][0] += a.y * b1.x; acc[r][0] += a.z * b2.x; acc[r][0] += a.w * b3.x;
                acc[r][1] += a.x * b0.y; acc[r][1] += a.y * b1.y; acc[r][1] += a.z * b2.y; acc[r][1] += a.w * b3.y;
                acc[r][2] += a.x * b0.z; acc[r][2] += a.y * b1.z; acc[r][2] += a.z * b2.z; acc[r][2] += a.w * b3.z;
                acc[r][3] += a.x * b0.w; acc[r][3] += a.y * b1.w; acc[r][3] += a.z * b2.w; acc[r][3] += a.w * b3.w;
            }
        }
    }
    float4 bv = *(const float4*)(bias + col0 + tx * 4);
#pragma unroll
    for (int r = 0; r < 4; ++r) {
        int gr = row0 + ty * 4 + r;
        if (gr < N) {
            float4 o;
            o.x = acc[r][0] + bv.x;
            o.y = acc[r][1] + bv.y;
            o.z = acc[r][2] + bv.z;
            o.w = acc[r][3] + bv.w;
            if (doRelu) {
                o.x = fmaxf(o.x, 0.f); o.y = fmaxf(o.y, 0.f);
                o.z = fmaxf(o.z, 0.f); o.w = fmaxf(o.w, 0.f);
            }
            *(float4*)(out + (size_t)gr * 128 + col0 + tx * 4) = o;
        }
    }
}

extern "C" void kernel_launch(void* const* d_in, const int* in_sizes, int n_in,
                              void* d_out, int out_size, void* d_ws, size_t ws_size,
                              hipStream_t stream)
{
    const float* h   = (const float*)d_in[0];
    const int*   src = (const int*)d_in[1];
    const int*   dst = (const int*)d_in[2];
    const float* Wm1 = (const float*)d_in[3];
    const float* bm1 = (const float*)d_in[4];
    const float* Wm2 = (const float*)d_in[5];
    const float* bm2 = (const float*)d_in[6];
    const float* Wm3 = (const float*)d_in[7];
    const float* bm3 = (const float*)d_in[8];
    const float* Wa1 = (const float*)d_in[9];
    const float* ba1 = (const float*)d_in[10];
    const float* Wa2 = (const float*)d_in[11];
    const float* ba2 = (const float*)d_in[12];
    const float* Wa3 = (const float*)d_in[13];
    const float* ba3 = (const float*)d_in[14];
    const float* Wc1 = (const float*)d_in[15];
    const float* bc1 = (const float*)d_in[16];
    const float* Wc2 = (const float*)d_in[17];
    const float* bc2 = (const float*)d_in[18];

    const int N = in_sizes[0] / NDIM;
    const int E = in_sizes[1];
    float* out = (float*)d_out;

    // workspace layout
    float* bufA = (float*)d_ws;                    // N*128
    float* bufB = bufA + (size_t)N * NDIM;         // N*128
    float* proj = bufB + (size_t)N * NDIM;         // N*8
    int* cnt    = (int*)(proj + (size_t)N * 8);    // N
    int* offs   = cnt + N;                         // N+1
    int* cursor = offs + N + 1;                    // N
    int* bsums  = cursor + N;                      // 128
    int* perm   = bsums + 128;                     // E

    hipMemsetAsync(cnt, 0, (size_t)N * sizeof(int), stream);

    k_proj<<<256, 256, 0, stream>>>(h, Wa1, Wa2, Wa3, proj, N);
    k_hist<<<(E + 255) / 256, 256, 0, stream>>>(dst, cnt, E);

    int nb = (N + 511) / 512;
    k_scan1<<<nb, 512, 0, stream>>>(cnt, offs, bsums, N);
    k_scan2<<<1, 128, 0, stream>>>(bsums, nb);
    k_scan3<<<nb, 512, 0, stream>>>(offs, bsums, cursor, N, E);

    k_edge<<<(E + 255) / 256, 256, 0, stream>>>(src, dst, cursor, perm, E);

    dim3 ggrid((N + GBM - 1) / GBM, 128 / GBN);
    // 3-layer message MLP in node domain (msg ends in bufA)
    k_gemm<<<ggrid, 256, 0, stream>>>(h,    nullptr, Wm1, nullptr, bm1, bufA, N, 1);
    k_gemm<<<ggrid, 256, 0, stream>>>(bufA, nullptr, Wm2, nullptr, bm2, bufB, N, 1);
    k_gemm<<<ggrid, 256, 0, stream>>>(bufB, nullptr, Wm3, nullptr, bm3, bufA, N, 1);

    // aggregation: hneigh in bufB (reads msg=bufA)
    k_aggr<<<N, 128, 0, stream>>>(bufA, proj, offs, perm, ba1, ba2, ba3, bufB, N);

    // out = relu(h@Wc1[:128] + hneigh@Wc1[128:] + bc1) @ Wc2 + bc2
    k_gemm<<<ggrid, 256, 0, stream>>>(h, bufB, Wc1, Wc1 + 128 * 128, bc1, bufA, N, 1);
    k_gemm<<<ggrid, 256, 0, stream>>>(bufA, nullptr, Wc2, nullptr, bc2, out, N, 0);
}

// Round 3
// 291.750 us; speedup vs baseline: 1.8223x; 1.4267x over previous
//
#include <hip/hip_runtime.h>

#define NDIM 128

typedef __attribute__((ext_vector_type(8))) short s8v;   // 8 bf16 in 4 VGPRs
typedef __attribute__((ext_vector_type(4))) float f4v;   // MFMA accumulator

// ---------------- per-node attention projections: s_k = h.Wa_k[0:128], d_k = h.Wa_k[128:256]
__global__ void k_proj(const float* __restrict__ h,
                       const float* __restrict__ Wa1,
                       const float* __restrict__ Wa2,
                       const float* __restrict__ Wa3,
                       float* __restrict__ proj, int N)
{
    int lane = threadIdx.x & 63;
    int wid  = blockIdx.x * (blockDim.x >> 6) + (threadIdx.x >> 6);
    int nw   = gridDim.x * (blockDim.x >> 6);
    float w1s0 = Wa1[lane], w1s1 = Wa1[64 + lane], w1d0 = Wa1[128 + lane], w1d1 = Wa1[192 + lane];
    float w2s0 = Wa2[lane], w2s1 = Wa2[64 + lane], w2d0 = Wa2[128 + lane], w2d1 = Wa2[192 + lane];
    float w3s0 = Wa3[lane], w3s1 = Wa3[64 + lane], w3d0 = Wa3[128 + lane], w3d1 = Wa3[192 + lane];
    for (int n = wid; n < N; n += nw) {
        float h0 = h[(size_t)n * NDIM + lane];
        float h1 = h[(size_t)n * NDIM + 64 + lane];
        float s1 = h0 * w1s0 + h1 * w1s1;
        float s2 = h0 * w2s0 + h1 * w2s1;
        float s3 = h0 * w3s0 + h1 * w3s1;
        float d1 = h0 * w1d0 + h1 * w1d1;
        float d2 = h0 * w2d0 + h1 * w2d1;
        float d3 = h0 * w3d0 + h1 * w3d1;
#pragma unroll
        for (int m = 1; m < 64; m <<= 1) {
            s1 += __shfl_xor(s1, m);
            s2 += __shfl_xor(s2, m);
            s3 += __shfl_xor(s3, m);
            d1 += __shfl_xor(d1, m);
            d2 += __shfl_xor(d2, m);
            d3 += __shfl_xor(d3, m);
        }
        if (lane == 0) {
            *(float4*)(proj + (size_t)n * 8)     = make_float4(s1, s2, s3, 0.f);
            *(float4*)(proj + (size_t)n * 8 + 4) = make_float4(d1, d2, d3, 0.f);
        }
    }
}

// ---------------- dst histogram
__global__ void k_hist(const int* __restrict__ dst, int* __restrict__ cnt, int E)
{
    int i = blockIdx.x * blockDim.x + threadIdx.x;
    if (i < E) atomicAdd(&cnt[dst[i]], 1);
}

// ---------------- hierarchical exclusive scan (chunk 512)
__global__ void k_scan1(const int* __restrict__ cnt, int* __restrict__ offs,
                        int* __restrict__ bsums, int N)
{
    __shared__ int s[512];
    int i = blockIdx.x * 512 + threadIdx.x;
    int v = (i < N) ? cnt[i] : 0;
    s[threadIdx.x] = v;
    __syncthreads();
    for (int d = 1; d < 512; d <<= 1) {
        int t = (threadIdx.x >= d) ? s[threadIdx.x - d] : 0;
        __syncthreads();
        s[threadIdx.x] += t;
        __syncthreads();
    }
    if (i < N) offs[i] = s[threadIdx.x] - v;
    if (threadIdx.x == 511) bsums[blockIdx.x] = s[511];
}

__global__ void k_scan2(int* __restrict__ bsums, int nb)
{
    __shared__ int s[128];
    int t = threadIdx.x;
    int v = (t < nb) ? bsums[t] : 0;
    s[t] = v;
    __syncthreads();
    for (int d = 1; d < 128; d <<= 1) {
        int u = (t >= d) ? s[t - d] : 0;
        __syncthreads();
        s[t] += u;
        __syncthreads();
    }
    if (t < nb) bsums[t] = s[t] - v;  // exclusive
}

__global__ void k_scan3(int* __restrict__ offs, const int* __restrict__ bsums,
                        int* __restrict__ cursor, int N, int E)
{
    int i = blockIdx.x * 512 + threadIdx.x;
    if (i < N) {
        int o = offs[i] + bsums[blockIdx.x];
        offs[i]   = o;
        cursor[i] = o;
    }
    if (i == 0) offs[N] = E;
}

// ---------------- minimal CSR build: scatter src ids into dst-grouped segments
__global__ void k_edge(const int* __restrict__ src, const int* __restrict__ dst,
                       int* __restrict__ cursor, int* __restrict__ perm, int E)
{
    int e = blockIdx.x * blockDim.x + threadIdx.x;
    if (e >= E) return;
    int d = dst[e];
    int pos = atomicAdd(&cursor[d], 1);
    perm[pos] = src[e];
}

// ---------------- per-dst-node aggregation (two-pass: att sums, then weighted msg sum)
__global__ __launch_bounds__(128) void k_aggr(const float* __restrict__ msg,
                                              const float* __restrict__ proj,
                                              const int* __restrict__ offs,
                                              const int* __restrict__ perm,
                                              const float* __restrict__ ba1,
                                              const float* __restrict__ ba2,
                                              const float* __restrict__ ba3,
                                              float* __restrict__ hneigh, int N)
{
    int n   = blockIdx.x;
    int tid = threadIdx.x;
    int o0 = offs[n], o1 = offs[n + 1];
    int deg = o1 - o0;
    if (deg == 0) {
        hneigh[(size_t)n * NDIM + tid] = 0.f;
        return;
    }
    float dd1 = proj[(size_t)n * 8 + 4];
    float dd2 = proj[(size_t)n * 8 + 5];
    float dd3 = proj[(size_t)n * 8 + 6];
    float b1 = ba1[0], b2 = ba2[0], b3 = ba3[0];

    // ---- pass 1: per-dst attention denominators
    float s1 = 0.f, s2 = 0.f, s3 = 0.f;
    for (int i = o0 + tid; i < o1; i += 128) {
        int s = perm[i];
        float4 sp = *(const float4*)(proj + (size_t)s * 8);
        s1 += __expf(fmaxf(sp.x + dd1 + b1, 0.f));
        s2 += __expf(fmaxf(sp.y + dd2 + b2, 0.f));
        s3 += __expf(fmaxf(sp.z + dd3 + b3, 0.f));
    }
#pragma unroll
    for (int m = 1; m < 64; m <<= 1) {
        s1 += __shfl_xor(s1, m);
        s2 += __shfl_xor(s2, m);
        s3 += __shfl_xor(s3, m);
    }
    __shared__ float red[2][3];
    if ((tid & 63) == 0) {
        int w = tid >> 6;
        red[w][0] = s1; red[w][1] = s2; red[w][2] = s3;
    }
    __syncthreads();
    float r1 = 1.f / (red[0][0] + red[1][0]);
    float r2 = 1.f / (red[0][1] + red[1][1]);
    float r3 = 1.f / (red[0][2] + red[1][2]);
    __syncthreads();

    // ---- pass 2: weighted message sum
    __shared__ int   ssrc[128];
    __shared__ float sw[128];
    float acc = 0.f;
    for (int base = o0; base < o1; base += 128) {
        int m = min(128, o1 - base);
        if (tid < m) {
            int s = perm[base + tid];
            float4 sp = *(const float4*)(proj + (size_t)s * 8);
            float a1 = __expf(fmaxf(sp.x + dd1 + b1, 0.f));
            float a2 = __expf(fmaxf(sp.y + dd2 + b2, 0.f));
            float a3 = __expf(fmaxf(sp.z + dd3 + b3, 0.f));
            sw[tid]   = (a1 * r1 + a2 * r2 + a3 * r3) * (1.f / 3.f);
            ssrc[tid] = s;
        }
        __syncthreads();
#pragma unroll 4
        for (int j = 0; j < m; ++j)
            acc += sw[j] * msg[(size_t)ssrc[j] * NDIM + tid];
        __syncthreads();
    }
    hneigh[(size_t)n * NDIM + tid] = acc * (1.f / (float)deg);
}

// ---------------- weight convert: W[k][c] fp32 -> transposed bf16 hi/lo planes Wt[c][k]
// out layout per matrix: [hi plane 16384][lo plane 16384] ushorts
__global__ void k_cvt_w(const float* __restrict__ w0, const float* __restrict__ w1,
                        const float* __restrict__ w2, const float* __restrict__ w3,
                        const float* __restrict__ w4, const float* __restrict__ w5,
                        unsigned short* __restrict__ out)
{
    const float* srcs[6] = {w0, w1, w2, w3, w4, w5};
    const float* W = srcs[blockIdx.y];
    int idx = blockIdx.x * 256 + threadIdx.x;   // = c*128 + k
    int c = idx >> 7, k = idx & 127;
    float x = W[k * 128 + c];
    unsigned xb = __float_as_uint(x);
    float hf = __uint_as_float(xb & 0xFFFF0000u);
    float rr = x - hf;                           // exact residual
    unsigned short hi = (unsigned short)(xb >> 16);
    unsigned short lo = (unsigned short)(__float_as_uint(rr) >> 16);
    unsigned short* ob = out + (size_t)blockIdx.y * 32768;
    ob[idx] = hi;
    ob[16384 + idx] = lo;
}

// ---------------- split-bf16 MFMA GEMM: out[N,128] = act(A@W (+A2@W2) + bias), K=128/pass
// BM=128 (8 waves x 16 rows), full 128 output cols per wave.
// W staged in LDS as hi/lo bf16 planes [col][k] with XOR swizzle; A split in-registers.
__global__ __launch_bounds__(512) void k_mfma(const float* __restrict__ A,
                                              const float* __restrict__ A2,
                                              const unsigned short* __restrict__ wt,
                                              const unsigned short* __restrict__ wt2,
                                              const float* __restrict__ bias,
                                              float* __restrict__ out,
                                              int N, int doRelu)
{
    __shared__ unsigned short Ws[2 * 128 * 128];   // 64 KB: hi plane, lo plane
    int tid  = threadIdx.x;
    int lane = tid & 63;
    int wid  = tid >> 6;
    int ln   = lane & 15;
    int g    = lane >> 4;
    int row0 = blockIdx.x * 128 + wid * 16;
    int rA   = min(row0 + ln, N - 1);

    f4v acc[8] = {};
    int npass = (A2 != nullptr) ? 2 : 1;
    for (int pass = 0; pass < npass; ++pass) {
        const float* Ap = pass ? A2 : A;
        const unsigned short* wp = pass ? wt2 : wt;
        if (pass) __syncthreads();   // all waves done reading Ws of pass 0
        // stage W hi/lo planes (4096 x short8 chunks, coalesced reads, swizzled writes)
#pragma unroll
        for (int i = 0; i < 8; ++i) {
            int c     = tid + 512 * i;
            int plane = c >> 11;
            int cc    = c & 2047;
            int col   = cc >> 4;
            int k0    = (cc & 15) << 3;
            s8v v = *(const s8v*)(wp + plane * 16384 + col * 128 + k0);
            int swz = (col * 128 + k0) ^ ((col & 7) << 3);
            *(s8v*)(&Ws[plane * 16384 + swz]) = v;
        }
        __syncthreads();
        const float* arow = Ap + (size_t)rA * 128 + g * 8;
#pragma unroll
        for (int ks = 0; ks < 4; ++ks) {
            // load 8 fp32 of this lane's A fragment; split into bf16 hi + lo
            float4 x0 = *(const float4*)(arow + ks * 32);
            float4 x1 = *(const float4*)(arow + ks * 32 + 4);
            float xs[8] = {x0.x, x0.y, x0.z, x0.w, x1.x, x1.y, x1.z, x1.w};
            s8v ahi, alo;
#pragma unroll
            for (int j = 0; j < 8; ++j) {
                unsigned xb = __float_as_uint(xs[j]);
                float hf = __uint_as_float(xb & 0xFFFF0000u);
                float rr = xs[j] - hf;
                ahi[j] = (short)(xb >> 16);
                alo[j] = (short)(__float_as_uint(rr) >> 16);
            }
#pragma unroll
            for (int ct = 0; ct < 8; ++ct) {
                int swz = ((ct * 16 + ln) * 128 + ks * 32 + g * 8) ^ ((ln & 7) << 3);
                s8v wh = *(const s8v*)(&Ws[swz]);
                s8v wl = *(const s8v*)(&Ws[16384 + swz]);
                acc[ct] = __builtin_amdgcn_mfma_f32_16x16x32_bf16(ahi, wh, acc[ct], 0, 0, 0);
                acc[ct] = __builtin_amdgcn_mfma_f32_16x16x32_bf16(alo, wh, acc[ct], 0, 0, 0);
                acc[ct] = __builtin_amdgcn_mfma_f32_16x16x32_bf16(ahi, wl, acc[ct], 0, 0, 0);
            }
        }
    }
    // epilogue: D frag is col=lane&15, row=(lane>>4)*4+reg
#pragma unroll
    for (int ct = 0; ct < 8; ++ct) {
        int col = ct * 16 + ln;
        float bv = bias[col];
#pragma unroll
        for (int q = 0; q < 4; ++q) {
            int orow = row0 + g * 4 + q;
            if (orow < N) {
                float o = acc[ct][q] + bv;
                if (doRelu) o = fmaxf(o, 0.f);
                out[(size_t)orow * 128 + col] = o;
            }
        }
    }
}

extern "C" void kernel_launch(void* const* d_in, const int* in_sizes, int n_in,
                              void* d_out, int out_size, void* d_ws, size_t ws_size,
                              hipStream_t stream)
{
    const float* h   = (const float*)d_in[0];
    const int*   src = (const int*)d_in[1];
    const int*   dst = (const int*)d_in[2];
    const float* Wm1 = (const float*)d_in[3];
    const float* bm1 = (const float*)d_in[4];
    const float* Wm2 = (const float*)d_in[5];
    const float* bm2 = (const float*)d_in[6];
    const float* Wm3 = (const float*)d_in[7];
    const float* bm3 = (const float*)d_in[8];
    const float* Wa1 = (const float*)d_in[9];
    const float* ba1 = (const float*)d_in[10];
    const float* Wa2 = (const float*)d_in[11];
    const float* ba2 = (const float*)d_in[12];
    const float* Wa3 = (const float*)d_in[13];
    const float* ba3 = (const float*)d_in[14];
    const float* Wc1 = (const float*)d_in[15];
    const float* bc1 = (const float*)d_in[16];
    const float* Wc2 = (const float*)d_in[17];
    const float* bc2 = (const float*)d_in[18];

    const int N = in_sizes[0] / NDIM;
    const int E = in_sizes[1];
    float* out = (float*)d_out;

    // workspace layout (wt first for 16B alignment)
    unsigned short* wt = (unsigned short*)d_ws;            // 6 * 32768 ushorts = 384 KB
    float* bufA = (float*)((char*)d_ws + 6 * 32768 * 2);   // N*128
    float* bufB = bufA + (size_t)N * NDIM;                 // N*128
    float* proj = bufB + (size_t)N * NDIM;                 // N*8
    int* cnt    = (int*)(proj + (size_t)N * 8);            // N
    int* offs   = cnt + N;                                 // N+1
    int* cursor = offs + N + 1;                            // N
    int* bsums  = cursor + N;                              // 128
    int* perm   = bsums + 128;                             // E

    const unsigned short* wt_m1  = wt;
    const unsigned short* wt_m2  = wt + 1 * 32768;
    const unsigned short* wt_m3  = wt + 2 * 32768;
    const unsigned short* wt_c1a = wt + 3 * 32768;
    const unsigned short* wt_c1b = wt + 4 * 32768;
    const unsigned short* wt_c2  = wt + 5 * 32768;

    hipMemsetAsync(cnt, 0, (size_t)N * sizeof(int), stream);

    k_cvt_w<<<dim3(64, 6), 256, 0, stream>>>(Wm1, Wm2, Wm3, Wc1, Wc1 + 128 * 128, Wc2, wt);
    k_proj<<<256, 256, 0, stream>>>(h, Wa1, Wa2, Wa3, proj, N);
    k_hist<<<(E + 255) / 256, 256, 0, stream>>>(dst, cnt, E);

    int nb = (N + 511) / 512;
    k_scan1<<<nb, 512, 0, stream>>>(cnt, offs, bsums, N);
    k_scan2<<<1, 128, 0, stream>>>(bsums, nb);
    k_scan3<<<nb, 512, 0, stream>>>(offs, bsums, cursor, N, E);

    k_edge<<<(E + 255) / 256, 256, 0, stream>>>(src, dst, cursor, perm, E);

    int gb = (N + 127) / 128;
    // 3-layer message MLP in node domain (msg ends in bufA)
    k_mfma<<<gb, 512, 0, stream>>>(h,    nullptr, wt_m1, nullptr, bm1, bufA, N, 1);
    k_mfma<<<gb, 512, 0, stream>>>(bufA, nullptr, wt_m2, nullptr, bm2, bufB, N, 1);
    k_mfma<<<gb, 512, 0, stream>>>(bufB, nullptr, wt_m3, nullptr, bm3, bufA, N, 1);

    // aggregation: hneigh in bufB (reads msg=bufA)
    k_aggr<<<N, 128, 0, stream>>>(bufA, proj, offs, perm, ba1, ba2, ba3, bufB, N);

    // out = relu(h@Wc1[:128] + hneigh@Wc1[128:] + bc1) @ Wc2 + bc2
    k_mfma<<<gb, 512, 0, stream>>>(h, bufB, wt_c1a, wt_c1b, bc1, bufA, N, 1);
    k_mfma<<<gb, 512, 0, stream>>>(bufA, nullptr, wt_c2, nullptr, bc2, out, N, 0);
}

// Round 4
// 290.824 us; speedup vs baseline: 1.8281x; 1.0032x over previous
//
#include <hip/hip_runtime.h>

#define NDIM 128

typedef __attribute__((ext_vector_type(8))) short s8v;   // 8 bf16 in 4 VGPRs
typedef __attribute__((ext_vector_type(4))) float f4v;   // MFMA accumulator

__device__ inline unsigned short f2bf_rne(float x) {
    unsigned u = __float_as_uint(x);
    unsigned r = u + 0x7FFFu + ((u >> 16) & 1u);
    return (unsigned short)(r >> 16);
}
__device__ inline float bf2f(unsigned short b) {
    return __uint_as_float(((unsigned)b) << 16);
}

// ---------------- per-node attention projections: s_k = h.Wa_k[0:128], d_k = h.Wa_k[128:256]
__global__ void k_proj(const float* __restrict__ h,
                       const float* __restrict__ Wa1,
                       const float* __restrict__ Wa2,
                       const float* __restrict__ Wa3,
                       float* __restrict__ proj, int N)
{
    int lane = threadIdx.x & 63;
    int wid  = blockIdx.x * (blockDim.x >> 6) + (threadIdx.x >> 6);
    int nw   = gridDim.x * (blockDim.x >> 6);
    float w1s0 = Wa1[lane], w1s1 = Wa1[64 + lane], w1d0 = Wa1[128 + lane], w1d1 = Wa1[192 + lane];
    float w2s0 = Wa2[lane], w2s1 = Wa2[64 + lane], w2d0 = Wa2[128 + lane], w2d1 = Wa2[192 + lane];
    float w3s0 = Wa3[lane], w3s1 = Wa3[64 + lane], w3d0 = Wa3[128 + lane], w3d1 = Wa3[192 + lane];
    for (int n = wid; n < N; n += nw) {
        float h0 = h[(size_t)n * NDIM + lane];
        float h1 = h[(size_t)n * NDIM + 64 + lane];
        float s1 = h0 * w1s0 + h1 * w1s1;
        float s2 = h0 * w2s0 + h1 * w2s1;
        float s3 = h0 * w3s0 + h1 * w3s1;
        float d1 = h0 * w1d0 + h1 * w1d1;
        float d2 = h0 * w2d0 + h1 * w2d1;
        float d3 = h0 * w3d0 + h1 * w3d1;
#pragma unroll
        for (int m = 1; m < 64; m <<= 1) {
            s1 += __shfl_xor(s1, m);
            s2 += __shfl_xor(s2, m);
            s3 += __shfl_xor(s3, m);
            d1 += __shfl_xor(d1, m);
            d2 += __shfl_xor(d2, m);
            d3 += __shfl_xor(d3, m);
        }
        if (lane == 0) {
            *(float4*)(proj + (size_t)n * 8)     = make_float4(s1, s2, s3, 0.f);
            *(float4*)(proj + (size_t)n * 8 + 4) = make_float4(d1, d2, d3, 0.f);
        }
    }
}

// ---------------- dst histogram
__global__ void k_hist(const int* __restrict__ dst, int* __restrict__ cnt, int E)
{
    int i = blockIdx.x * blockDim.x + threadIdx.x;
    if (i < E) atomicAdd(&cnt[dst[i]], 1);
}

// ---------------- hierarchical exclusive scan (chunk 512)
__global__ void k_scan1(const int* __restrict__ cnt, int* __restrict__ offs,
                        int* __restrict__ bsums, int N)
{
    __shared__ int s[512];
    int i = blockIdx.x * 512 + threadIdx.x;
    int v = (i < N) ? cnt[i] : 0;
    s[threadIdx.x] = v;
    __syncthreads();
    for (int d = 1; d < 512; d <<= 1) {
        int t = (threadIdx.x >= d) ? s[threadIdx.x - d] : 0;
        __syncthreads();
        s[threadIdx.x] += t;
        __syncthreads();
    }
    if (i < N) offs[i] = s[threadIdx.x] - v;
    if (threadIdx.x == 511) bsums[blockIdx.x] = s[511];
}

__global__ void k_scan2(int* __restrict__ bsums, int nb)
{
    __shared__ int s[128];
    int t = threadIdx.x;
    int v = (t < nb) ? bsums[t] : 0;
    s[t] = v;
    __syncthreads();
    for (int d = 1; d < 128; d <<= 1) {
        int u = (t >= d) ? s[t - d] : 0;
        __syncthreads();
        s[t] += u;
        __syncthreads();
    }
    if (t < nb) bsums[t] = s[t] - v;  // exclusive
}

__global__ void k_scan3(int* __restrict__ offs, const int* __restrict__ bsums,
                        int* __restrict__ cursor, int N, int E)
{
    int i = blockIdx.x * 512 + threadIdx.x;
    if (i < N) {
        int o = offs[i] + bsums[blockIdx.x];
        offs[i]   = o;
        cursor[i] = o;
    }
    if (i == 0) offs[N] = E;
}

// ---------------- minimal CSR build: scatter src ids into dst-grouped segments
__global__ void k_edge(const int* __restrict__ src, const int* __restrict__ dst,
                       int* __restrict__ cursor, int* __restrict__ perm, int E)
{
    int e = blockIdx.x * blockDim.x + threadIdx.x;
    if (e >= E) return;
    int d = dst[e];
    int pos = atomicAdd(&cursor[d], 1);
    perm[pos] = src[e];
}

// ---------------- per-dst-node aggregation, one wave per node, bf16 msg gather
// pass 1: att denominators (chunk-0 numerators cached in registers)
// pass 2: weighted bf16 msg sum, weights broadcast via shuffles
__global__ __launch_bounds__(256) void k_aggr(const unsigned short* __restrict__ msgb,
                                              const float* __restrict__ proj,
                                              const int* __restrict__ offs,
                                              const int* __restrict__ perm,
                                              const float* __restrict__ ba1,
                                              const float* __restrict__ ba2,
                                              const float* __restrict__ ba3,
                                              float* __restrict__ hneigh, int N)
{
    int lane = threadIdx.x & 63;
    int n    = blockIdx.x * 4 + (threadIdx.x >> 6);
    if (n >= N) return;
    int o0 = offs[n], o1 = offs[n + 1];
    int deg = o1 - o0;
    float2* outp = (float2*)(hneigh + (size_t)n * NDIM);
    if (deg == 0) {
        outp[lane] = make_float2(0.f, 0.f);
        return;
    }
    float dd1 = proj[(size_t)n * 8 + 4];
    float dd2 = proj[(size_t)n * 8 + 5];
    float dd3 = proj[(size_t)n * 8 + 6];
    float b1 = ba1[0], b2 = ba2[0], b3 = ba3[0];

    // ---- pass 1: denominators; cache chunk-0 numerators + src in registers
    int   m0 = min(deg, 64);
    int   sc = 0;
    float a1c = 0.f, a2c = 0.f, a3c = 0.f;
    if (lane < m0) {
        sc = perm[o0 + lane];
        float4 sp = *(const float4*)(proj + (size_t)sc * 8);
        a1c = __expf(fmaxf(sp.x + dd1 + b1, 0.f));
        a2c = __expf(fmaxf(sp.y + dd2 + b2, 0.f));
        a3c = __expf(fmaxf(sp.z + dd3 + b3, 0.f));
    }
    float s1 = a1c, s2 = a2c, s3 = a3c;
    for (int i = o0 + 64 + lane; i < o1; i += 64) {
        int s = perm[i];
        float4 sp = *(const float4*)(proj + (size_t)s * 8);
        s1 += __expf(fmaxf(sp.x + dd1 + b1, 0.f));
        s2 += __expf(fmaxf(sp.y + dd2 + b2, 0.f));
        s3 += __expf(fmaxf(sp.z + dd3 + b3, 0.f));
    }
#pragma unroll
    for (int m = 1; m < 64; m <<= 1) {
        s1 += __shfl_xor(s1, m);
        s2 += __shfl_xor(s2, m);
        s3 += __shfl_xor(s3, m);
    }
    float r1 = 1.f / s1, r2 = 1.f / s2, r3 = 1.f / s3;

    // ---- pass 2: weighted message sum (bf16 rows, 4B/lane)
    float2 acc = make_float2(0.f, 0.f);
    {
        float wv = (a1c * r1 + a2c * r2 + a3c * r3) * (1.f / 3.f);
        for (int j = 0; j < m0; ++j) {
            int   s = __shfl(sc, j);
            float w = __shfl(wv, j);
            ushort2 v = *(const ushort2*)(msgb + (size_t)s * NDIM + lane * 2);
            acc.x += w * bf2f(v.x);
            acc.y += w * bf2f(v.y);
        }
    }
    for (int base = o0 + 64; base < o1; base += 64) {
        int m  = min(64, o1 - base);
        int sv = 0;
        float wv = 0.f;
        if (lane < m) {
            sv = perm[base + lane];
            float4 sp = *(const float4*)(proj + (size_t)sv * 8);
            float a1 = __expf(fmaxf(sp.x + dd1 + b1, 0.f));
            float a2 = __expf(fmaxf(sp.y + dd2 + b2, 0.f));
            float a3 = __expf(fmaxf(sp.z + dd3 + b3, 0.f));
            wv = (a1 * r1 + a2 * r2 + a3 * r3) * (1.f / 3.f);
        }
        for (int j = 0; j < m; ++j) {
            int   s = __shfl(sv, j);
            float w = __shfl(wv, j);
            ushort2 v = *(const ushort2*)(msgb + (size_t)s * NDIM + lane * 2);
            acc.x += w * bf2f(v.x);
            acc.y += w * bf2f(v.y);
        }
    }
    float inv = 1.f / (float)deg;
    outp[lane] = make_float2(acc.x * inv, acc.y * inv);
}

// ---------------- weight convert: W[k][c] fp32 -> transposed bf16 hi/lo planes Wt[c][k]
__global__ void k_cvt_w(const float* __restrict__ w0, const float* __restrict__ w1,
                        const float* __restrict__ w2, const float* __restrict__ w3,
                        const float* __restrict__ w4, const float* __restrict__ w5,
                        unsigned short* __restrict__ out)
{
    const float* srcs[6] = {w0, w1, w2, w3, w4, w5};
    const float* W = srcs[blockIdx.y];
    int idx = blockIdx.x * 256 + threadIdx.x;   // = c*128 + k
    int c = idx >> 7, k = idx & 127;
    float x = W[k * 128 + c];
    unsigned xb = __float_as_uint(x);
    float hf = __uint_as_float(xb & 0xFFFF0000u);
    float rr = x - hf;                           // exact residual
    unsigned short hi = (unsigned short)(xb >> 16);
    unsigned short lo = (unsigned short)(__float_as_uint(rr) >> 16);
    unsigned short* ob = out + (size_t)blockIdx.y * 32768;
    ob[idx] = hi;
    ob[16384 + idx] = lo;
}

// ---------------- split-bf16 MFMA GEMM: out[N,128] = act(A@W (+A2@W2) + bias), K=128/pass
// BM=128 (8 waves x 16 rows), full 128 output cols per wave.
// W staged in LDS as hi/lo bf16 planes [col][k] with XOR swizzle; A split in-registers.
// outBf16: write bf16 (RNE) instead of fp32; safe in-place over A (each block
// reads only its own rows; __syncthreads before epilogue drains all reads).
__global__ __launch_bounds__(512) void k_mfma(const float* __restrict__ A,
                                              const float* __restrict__ A2,
                                              const unsigned short* __restrict__ wt,
                                              const unsigned short* __restrict__ wt2,
                                              const float* __restrict__ bias,
                                              float* __restrict__ out,
                                              int N, int doRelu, int outBf16)
{
    __shared__ unsigned short Ws[2 * 128 * 128];   // 64 KB: hi plane, lo plane
    int tid  = threadIdx.x;
    int lane = tid & 63;
    int wid  = tid >> 6;
    int ln   = lane & 15;
    int g    = lane >> 4;
    int row0 = blockIdx.x * 128 + wid * 16;
    int rA   = min(row0 + ln, N - 1);

    f4v acc[8] = {};
    int npass = (A2 != nullptr) ? 2 : 1;
    for (int pass = 0; pass < npass; ++pass) {
        const float* Ap = pass ? A2 : A;
        const unsigned short* wp = pass ? wt2 : wt;
        if (pass) __syncthreads();   // all waves done reading Ws of pass 0
        // stage W hi/lo planes (4096 x short8 chunks, coalesced reads, swizzled writes)
#pragma unroll
        for (int i = 0; i < 8; ++i) {
            int c     = tid + 512 * i;
            int plane = c >> 11;
            int cc    = c & 2047;
            int col   = cc >> 4;
            int k0    = (cc & 15) << 3;
            s8v v = *(const s8v*)(wp + plane * 16384 + col * 128 + k0);
            int swz = (col * 128 + k0) ^ ((col & 7) << 3);
            *(s8v*)(&Ws[plane * 16384 + swz]) = v;
        }
        __syncthreads();
        const float* arow = Ap + (size_t)rA * 128 + g * 8;
#pragma unroll
        for (int ks = 0; ks < 4; ++ks) {
            // load 8 fp32 of this lane's A fragment; split into bf16 hi + lo
            float4 x0 = *(const float4*)(arow + ks * 32);
            float4 x1 = *(const float4*)(arow + ks * 32 + 4);
            float xs[8] = {x0.x, x0.y, x0.z, x0.w, x1.x, x1.y, x1.z, x1.w};
            s8v ahi, alo;
#pragma unroll
            for (int j = 0; j < 8; ++j) {
                unsigned xb = __float_as_uint(xs[j]);
                float hf = __uint_as_float(xb & 0xFFFF0000u);
                float rr = xs[j] - hf;
                ahi[j] = (short)(xb >> 16);
                alo[j] = (short)(__float_as_uint(rr) >> 16);
            }
#pragma unroll
            for (int ct = 0; ct < 8; ++ct) {
                int swz = ((ct * 16 + ln) * 128 + ks * 32 + g * 8) ^ ((ln & 7) << 3);
                s8v wh = *(const s8v*)(&Ws[swz]);
                s8v wl = *(const s8v*)(&Ws[16384 + swz]);
                acc[ct] = __builtin_amdgcn_mfma_f32_16x16x32_bf16(ahi, wh, acc[ct], 0, 0, 0);
                acc[ct] = __builtin_amdgcn_mfma_f32_16x16x32_bf16(alo, wh, acc[ct], 0, 0, 0);
                acc[ct] = __builtin_amdgcn_mfma_f32_16x16x32_bf16(ahi, wl, acc[ct], 0, 0, 0);
            }
        }
    }
    __syncthreads();   // drain all A reads before (possibly in-place) writes
    // epilogue: D frag is col=lane&15, row=(lane>>4)*4+reg
#pragma unroll
    for (int ct = 0; ct < 8; ++ct) {
        int col = ct * 16 + ln;
        float bv = bias[col];
#pragma unroll
        for (int q = 0; q < 4; ++q) {
            int orow = row0 + g * 4 + q;
            if (orow < N) {
                float o = acc[ct][q] + bv;
                if (doRelu) o = fmaxf(o, 0.f);
                if (outBf16)
                    ((unsigned short*)out)[(size_t)orow * 128 + col] = f2bf_rne(o);
                else
                    out[(size_t)orow * 128 + col] = o;
            }
        }
    }
}

extern "C" void kernel_launch(void* const* d_in, const int* in_sizes, int n_in,
                              void* d_out, int out_size, void* d_ws, size_t ws_size,
                              hipStream_t stream)
{
    const float* h   = (const float*)d_in[0];
    const int*   src = (const int*)d_in[1];
    const int*   dst = (const int*)d_in[2];
    const float* Wm1 = (const float*)d_in[3];
    const float* bm1 = (const float*)d_in[4];
    const float* Wm2 = (const float*)d_in[5];
    const float* bm2 = (const float*)d_in[6];
    const float* Wm3 = (const float*)d_in[7];
    const float* bm3 = (const float*)d_in[8];
    const float* Wa1 = (const float*)d_in[9];
    const float* ba1 = (const float*)d_in[10];
    const float* Wa2 = (const float*)d_in[11];
    const float* ba2 = (const float*)d_in[12];
    const float* Wa3 = (const float*)d_in[13];
    const float* ba3 = (const float*)d_in[14];
    const float* Wc1 = (const float*)d_in[15];
    const float* bc1 = (const float*)d_in[16];
    const float* Wc2 = (const float*)d_in[17];
    const float* bc2 = (const float*)d_in[18];

    const int N = in_sizes[0] / NDIM;
    const int E = in_sizes[1];
    float* out = (float*)d_out;

    // workspace layout (wt first for 16B alignment)
    unsigned short* wt = (unsigned short*)d_ws;            // 6 * 32768 ushorts = 384 KB
    float* bufA = (float*)((char*)d_ws + 6 * 32768 * 2);   // N*128
    float* bufB = bufA + (size_t)N * NDIM;                 // N*128
    float* proj = bufB + (size_t)N * NDIM;                 // N*8
    int* cnt    = (int*)(proj + (size_t)N * 8);            // N
    int* offs   = cnt + N;                                 // N+1
    int* cursor = offs + N + 1;                            // N
    int* bsums  = cursor + N;                              // 128
    int* perm   = bsums + 128;                             // E

    const unsigned short* wt_m1  = wt;
    const unsigned short* wt_m2  = wt + 1 * 32768;
    const unsigned short* wt_m3  = wt + 2 * 32768;
    const unsigned short* wt_c1a = wt + 3 * 32768;
    const unsigned short* wt_c1b = wt + 4 * 32768;
    const unsigned short* wt_c2  = wt + 5 * 32768;

    hipMemsetAsync(cnt, 0, (size_t)N * sizeof(int), stream);

    k_cvt_w<<<dim3(64, 6), 256, 0, stream>>>(Wm1, Wm2, Wm3, Wc1, Wc1 + 128 * 128, Wc2, wt);
    k_proj<<<256, 256, 0, stream>>>(h, Wa1, Wa2, Wa3, proj, N);
    k_hist<<<(E + 255) / 256, 256, 0, stream>>>(dst, cnt, E);

    int nb = (N + 511) / 512;
    k_scan1<<<nb, 512, 0, stream>>>(cnt, offs, bsums, N);
    k_scan2<<<1, 128, 0, stream>>>(bsums, nb);
    k_scan3<<<nb, 512, 0, stream>>>(offs, bsums, cursor, N, E);

    k_edge<<<(E + 255) / 256, 256, 0, stream>>>(src, dst, cursor, perm, E);

    int gb = (N + 127) / 128;
    // 3-layer message MLP in node domain; layer 3 writes bf16 msg in-place over bufB
    k_mfma<<<gb, 512, 0, stream>>>(h,    nullptr, wt_m1, nullptr, bm1, bufA, N, 1, 0);
    k_mfma<<<gb, 512, 0, stream>>>(bufA, nullptr, wt_m2, nullptr, bm2, bufB, N, 1, 0);
    k_mfma<<<gb, 512, 0, stream>>>(bufB, nullptr, wt_m3, nullptr, bm3, bufB, N, 1, 1);
    unsigned short* msgb = (unsigned short*)bufB;

    // aggregation: hneigh -> bufA (bufA free after layer 2)
    k_aggr<<<(N + 3) / 4, 256, 0, stream>>>(msgb, proj, offs, perm, ba1, ba2, ba3, bufA, N);

    // out = relu(h@Wc1[:128] + hneigh@Wc1[128:] + bc1) @ Wc2 + bc2
    k_mfma<<<gb, 512, 0, stream>>>(h, bufA, wt_c1a, wt_c1b, bc1, bufB, N, 1, 0);
    k_mfma<<<gb, 512, 0, stream>>>(bufB, nullptr, wt_c2, nullptr, bc2, out, N, 0, 0);
}

// Round 5
// 268.143 us; speedup vs baseline: 1.9827x; 1.0846x over previous
//
#include <hip/hip_runtime.h>

#define NDIM 128

typedef __attribute__((ext_vector_type(8))) short s8v;   // 8 bf16 in 4 VGPRs
typedef __attribute__((ext_vector_type(4))) float f4v;   // MFMA accumulator

__device__ inline unsigned short f2bf_rne(float x) {
    unsigned u = __float_as_uint(x);
    unsigned r = u + 0x7FFFu + ((u >> 16) & 1u);
    return (unsigned short)(r >> 16);
}
__device__ inline float bf2f(unsigned short b) {
    return __uint_as_float(((unsigned)b) << 16);
}

// ---------------- per-node attention projections: s_k = h.Wa_k[0:128], d_k = h.Wa_k[128:256]
__global__ void k_proj(const float* __restrict__ h,
                       const float* __restrict__ Wa1,
                       const float* __restrict__ Wa2,
                       const float* __restrict__ Wa3,
                       float* __restrict__ proj, int N)
{
    int lane = threadIdx.x & 63;
    int wid  = blockIdx.x * (blockDim.x >> 6) + (threadIdx.x >> 6);
    int nw   = gridDim.x * (blockDim.x >> 6);
    float w1s0 = Wa1[lane], w1s1 = Wa1[64 + lane], w1d0 = Wa1[128 + lane], w1d1 = Wa1[192 + lane];
    float w2s0 = Wa2[lane], w2s1 = Wa2[64 + lane], w2d0 = Wa2[128 + lane], w2d1 = Wa2[192 + lane];
    float w3s0 = Wa3[lane], w3s1 = Wa3[64 + lane], w3d0 = Wa3[128 + lane], w3d1 = Wa3[192 + lane];
    for (int n = wid; n < N; n += nw) {
        float h0 = h[(size_t)n * NDIM + lane];
        float h1 = h[(size_t)n * NDIM + 64 + lane];
        float s1 = h0 * w1s0 + h1 * w1s1;
        float s2 = h0 * w2s0 + h1 * w2s1;
        float s3 = h0 * w3s0 + h1 * w3s1;
        float d1 = h0 * w1d0 + h1 * w1d1;
        float d2 = h0 * w2d0 + h1 * w2d1;
        float d3 = h0 * w3d0 + h1 * w3d1;
#pragma unroll
        for (int m = 1; m < 64; m <<= 1) {
            s1 += __shfl_xor(s1, m);
            s2 += __shfl_xor(s2, m);
            s3 += __shfl_xor(s3, m);
            d1 += __shfl_xor(d1, m);
            d2 += __shfl_xor(d2, m);
            d3 += __shfl_xor(d3, m);
        }
        if (lane == 0) {
            *(float4*)(proj + (size_t)n * 8)     = make_float4(s1, s2, s3, 0.f);
            *(float4*)(proj + (size_t)n * 8 + 4) = make_float4(d1, d2, d3, 0.f);
        }
    }
}

// ---------------- dst histogram
__global__ void k_hist(const int* __restrict__ dst, int* __restrict__ cnt, int E)
{
    int i = blockIdx.x * blockDim.x + threadIdx.x;
    if (i < E) atomicAdd(&cnt[dst[i]], 1);
}

// ---------------- hierarchical exclusive scan (chunk 512)
__global__ void k_scan1(const int* __restrict__ cnt, int* __restrict__ offs,
                        int* __restrict__ bsums, int N)
{
    __shared__ int s[512];
    int i = blockIdx.x * 512 + threadIdx.x;
    int v = (i < N) ? cnt[i] : 0;
    s[threadIdx.x] = v;
    __syncthreads();
    for (int d = 1; d < 512; d <<= 1) {
        int t = (threadIdx.x >= d) ? s[threadIdx.x - d] : 0;
        __syncthreads();
        s[threadIdx.x] += t;
        __syncthreads();
    }
    if (i < N) offs[i] = s[threadIdx.x] - v;
    if (threadIdx.x == 511) bsums[blockIdx.x] = s[511];
}

__global__ void k_scan2(int* __restrict__ bsums, int nb)
{
    __shared__ int s[128];
    int t = threadIdx.x;
    int v = (t < nb) ? bsums[t] : 0;
    s[t] = v;
    __syncthreads();
    for (int d = 1; d < 128; d <<= 1) {
        int u = (t >= d) ? s[t - d] : 0;
        __syncthreads();
        s[t] += u;
        __syncthreads();
    }
    if (t < nb) bsums[t] = s[t] - v;  // exclusive
}

__global__ void k_scan3(int* __restrict__ offs, const int* __restrict__ bsums,
                        int* __restrict__ cursor, int N, int E)
{
    int i = blockIdx.x * 512 + threadIdx.x;
    if (i < N) {
        int o = offs[i] + bsums[blockIdx.x];
        offs[i]   = o;
        cursor[i] = o;
    }
    if (i == 0) offs[N] = E;
}

// ---------------- minimal CSR build: scatter src ids into dst-grouped segments
__global__ void k_edge(const int* __restrict__ src, const int* __restrict__ dst,
                       int* __restrict__ cursor, int* __restrict__ perm, int E)
{
    int e = blockIdx.x * blockDim.x + threadIdx.x;
    if (e >= E) return;
    int d = dst[e];
    int pos = atomicAdd(&cursor[d], 1);
    perm[pos] = src[e];
}

// ---------------- per-dst-node aggregation, 16-lane group per node (4 nodes/wave)
// pass 1: att denominators (chunk-0 numerators cached in registers), 16 lanes/node
// pass 2: weighted bf16 msg sum; each group keeps one full row (16 x ushort8) in
// flight; 4 independent rows per wave for high MLP.
__global__ __launch_bounds__(256) void k_aggr(const unsigned short* __restrict__ msgb,
                                              const float* __restrict__ proj,
                                              const int* __restrict__ offs,
                                              const int* __restrict__ perm,
                                              const float* __restrict__ ba1,
                                              const float* __restrict__ ba2,
                                              const float* __restrict__ ba3,
                                              float* __restrict__ hneigh, int N)
{
    int tid  = threadIdx.x;
    int lane = tid & 63;
    int l    = lane & 15;          // lane within group
    int g    = lane >> 4;          // group 0..3
    int wvid = blockIdx.x * (blockDim.x >> 6) + (tid >> 6);
    int n    = wvid * 4 + g;       // node owned by this group
    bool alive = (n < N);

    int o0 = 0, o1 = 0;
    float dd1 = 0.f, dd2 = 0.f, dd3 = 0.f;
    if (alive) {
        o0 = offs[n];
        o1 = offs[n + 1];
        dd1 = proj[(size_t)n * 8 + 4];
        dd2 = proj[(size_t)n * 8 + 5];
        dd3 = proj[(size_t)n * 8 + 6];
    }
    int deg = o1 - o0;
    float b1 = ba1[0], b2 = ba2[0], b3 = ba3[0];

    // ---- pass 1: denominators; cache chunk-0 (<=16 edges) numerators + src in regs
    int   m0 = min(deg, 16);
    int   sc = 0;
    float a1c = 0.f, a2c = 0.f, a3c = 0.f;
    if (l < m0) {
        sc = perm[o0 + l];
        float4 sp = *(const float4*)(proj + (size_t)sc * 8);
        a1c = __expf(fmaxf(sp.x + dd1 + b1, 0.f));
        a2c = __expf(fmaxf(sp.y + dd2 + b2, 0.f));
        a3c = __expf(fmaxf(sp.z + dd3 + b3, 0.f));
    }
    float s1 = a1c, s2 = a2c, s3 = a3c;
    for (int i = o0 + 16 + l; i < o1; i += 16) {
        int s = perm[i];
        float4 sp = *(const float4*)(proj + (size_t)s * 8);
        s1 += __expf(fmaxf(sp.x + dd1 + b1, 0.f));
        s2 += __expf(fmaxf(sp.y + dd2 + b2, 0.f));
        s3 += __expf(fmaxf(sp.z + dd3 + b3, 0.f));
    }
#pragma unroll
    for (int m = 1; m < 16; m <<= 1) {   // group-local reduce
        s1 += __shfl_xor(s1, m);
        s2 += __shfl_xor(s2, m);
        s3 += __shfl_xor(s3, m);
    }
    float r1 = 1.f / s1, r2 = 1.f / s2, r3 = 1.f / s3;

    // ---- pass 2: weighted message sum; lane l covers columns l*8..l*8+7
    float acc[8] = {};
    int gbase = g << 4;
    {
        float wv = (a1c * r1 + a2c * r2 + a3c * r3) * (1.f / 3.f);
        for (int j = 0; j < m0; ++j) {
            int   s = __shfl(sc, gbase + j);
            float w = __shfl(wv, gbase + j);
            s8v v = *(const s8v*)(msgb + (size_t)s * NDIM + l * 8);
#pragma unroll
            for (int k = 0; k < 8; ++k)
                acc[k] += w * bf2f((unsigned short)v[k]);
        }
    }
    for (int base = o0 + 16; base < o1; base += 16) {
        int m  = min(16, o1 - base);
        int sv = 0;
        float wv = 0.f;
        if (l < m) {
            sv = perm[base + l];
            float4 sp = *(const float4*)(proj + (size_t)sv * 8);
            float a1 = __expf(fmaxf(sp.x + dd1 + b1, 0.f));
            float a2 = __expf(fmaxf(sp.y + dd2 + b2, 0.f));
            float a3 = __expf(fmaxf(sp.z + dd3 + b3, 0.f));
            wv = (a1 * r1 + a2 * r2 + a3 * r3) * (1.f / 3.f);
        }
        for (int j = 0; j < m; ++j) {
            int   s = __shfl(sv, gbase + j);
            float w = __shfl(wv, gbase + j);
            s8v v = *(const s8v*)(msgb + (size_t)s * NDIM + l * 8);
#pragma unroll
            for (int k = 0; k < 8; ++k)
                acc[k] += w * bf2f((unsigned short)v[k]);
        }
    }
    if (alive) {
        float inv = (deg > 0) ? 1.f / (float)deg : 0.f;
        float* op = hneigh + (size_t)n * NDIM + l * 8;
        *(float4*)(op)     = make_float4(acc[0] * inv, acc[1] * inv, acc[2] * inv, acc[3] * inv);
        *(float4*)(op + 4) = make_float4(acc[4] * inv, acc[5] * inv, acc[6] * inv, acc[7] * inv);
    }
}

// ---------------- weight convert: W[k][c] fp32 -> transposed bf16 hi/lo planes Wt[c][k]
__global__ void k_cvt_w(const float* __restrict__ w0, const float* __restrict__ w1,
                        const float* __restrict__ w2, const float* __restrict__ w3,
                        const float* __restrict__ w4, const float* __restrict__ w5,
                        unsigned short* __restrict__ out)
{
    const float* srcs[6] = {w0, w1, w2, w3, w4, w5};
    const float* W = srcs[blockIdx.y];
    int idx = blockIdx.x * 256 + threadIdx.x;   // = c*128 + k
    int c = idx >> 7, k = idx & 127;
    float x = W[k * 128 + c];
    unsigned xb = __float_as_uint(x);
    float hf = __uint_as_float(xb & 0xFFFF0000u);
    float rr = x - hf;                           // exact residual
    unsigned short hi = (unsigned short)(xb >> 16);
    unsigned short lo = (unsigned short)(__float_as_uint(rr) >> 16);
    unsigned short* ob = out + (size_t)blockIdx.y * 32768;
    ob[idx] = hi;
    ob[16384 + idx] = lo;
}

// ---------------- split-bf16 MFMA GEMM: out[N,128] = act(A@W (+A2@W2) + bias), K=128/pass
// BM=128 (8 waves x 16 rows), full 128 output cols per wave.
// W staged in LDS as hi/lo bf16 planes [col][k] with XOR swizzle; A split in-registers.
// outBf16: write bf16 (RNE) instead of fp32; safe in-place over A (each block
// reads only its own rows; __syncthreads before epilogue drains all reads).
__global__ __launch_bounds__(512) void k_mfma(const float* __restrict__ A,
                                              const float* __restrict__ A2,
                                              const unsigned short* __restrict__ wt,
                                              const unsigned short* __restrict__ wt2,
                                              const float* __restrict__ bias,
                                              float* __restrict__ out,
                                              int N, int doRelu, int outBf16)
{
    __shared__ unsigned short Ws[2 * 128 * 128];   // 64 KB: hi plane, lo plane
    int tid  = threadIdx.x;
    int lane = tid & 63;
    int wid  = tid >> 6;
    int ln   = lane & 15;
    int g    = lane >> 4;
    int row0 = blockIdx.x * 128 + wid * 16;
    int rA   = min(row0 + ln, N - 1);

    f4v acc[8] = {};
    int npass = (A2 != nullptr) ? 2 : 1;
    for (int pass = 0; pass < npass; ++pass) {
        const float* Ap = pass ? A2 : A;
        const unsigned short* wp = pass ? wt2 : wt;
        if (pass) __syncthreads();   // all waves done reading Ws of pass 0
        // stage W hi/lo planes (4096 x short8 chunks, coalesced reads, swizzled writes)
#pragma unroll
        for (int i = 0; i < 8; ++i) {
            int c     = tid + 512 * i;
            int plane = c >> 11;
            int cc    = c & 2047;
            int col   = cc >> 4;
            int k0    = (cc & 15) << 3;
            s8v v = *(const s8v*)(wp + plane * 16384 + col * 128 + k0);
            int swz = (col * 128 + k0) ^ ((col & 7) << 3);
            *(s8v*)(&Ws[plane * 16384 + swz]) = v;
        }
        __syncthreads();
        const float* arow = Ap + (size_t)rA * 128 + g * 8;
#pragma unroll
        for (int ks = 0; ks < 4; ++ks) {
            // load 8 fp32 of this lane's A fragment; split into bf16 hi + lo
            float4 x0 = *(const float4*)(arow + ks * 32);
            float4 x1 = *(const float4*)(arow + ks * 32 + 4);
            float xs[8] = {x0.x, x0.y, x0.z, x0.w, x1.x, x1.y, x1.z, x1.w};
            s8v ahi, alo;
#pragma unroll
            for (int j = 0; j < 8; ++j) {
                unsigned xb = __float_as_uint(xs[j]);
                float hf = __uint_as_float(xb & 0xFFFF0000u);
                float rr = xs[j] - hf;
                ahi[j] = (short)(xb >> 16);
                alo[j] = (short)(__float_as_uint(rr) >> 16);
            }
#pragma unroll
            for (int ct = 0; ct < 8; ++ct) {
                int swz = ((ct * 16 + ln) * 128 + ks * 32 + g * 8) ^ ((ln & 7) << 3);
                s8v wh = *(const s8v*)(&Ws[swz]);
                s8v wl = *(const s8v*)(&Ws[16384 + swz]);
                acc[ct] = __builtin_amdgcn_mfma_f32_16x16x32_bf16(ahi, wh, acc[ct], 0, 0, 0);
                acc[ct] = __builtin_amdgcn_mfma_f32_16x16x32_bf16(alo, wh, acc[ct], 0, 0, 0);
                acc[ct] = __builtin_amdgcn_mfma_f32_16x16x32_bf16(ahi, wl, acc[ct], 0, 0, 0);
            }
        }
    }
    __syncthreads();   // drain all A reads before (possibly in-place) writes
    // epilogue: D frag is col=lane&15, row=(lane>>4)*4+reg
#pragma unroll
    for (int ct = 0; ct < 8; ++ct) {
        int col = ct * 16 + ln;
        float bv = bias[col];
#pragma unroll
        for (int q = 0; q < 4; ++q) {
            int orow = row0 + g * 4 + q;
            if (orow < N) {
                float o = acc[ct][q] + bv;
                if (doRelu) o = fmaxf(o, 0.f);
                if (outBf16)
                    ((unsigned short*)out)[(size_t)orow * 128 + col] = f2bf_rne(o);
                else
                    out[(size_t)orow * 128 + col] = o;
            }
        }
    }
}

extern "C" void kernel_launch(void* const* d_in, const int* in_sizes, int n_in,
                              void* d_out, int out_size, void* d_ws, size_t ws_size,
                              hipStream_t stream)
{
    const float* h   = (const float*)d_in[0];
    const int*   src = (const int*)d_in[1];
    const int*   dst = (const int*)d_in[2];
    const float* Wm1 = (const float*)d_in[3];
    const float* bm1 = (const float*)d_in[4];
    const float* Wm2 = (const float*)d_in[5];
    const float* bm2 = (const float*)d_in[6];
    const float* Wm3 = (const float*)d_in[7];
    const float* bm3 = (const float*)d_in[8];
    const float* Wa1 = (const float*)d_in[9];
    const float* ba1 = (const float*)d_in[10];
    const float* Wa2 = (const float*)d_in[11];
    const float* ba2 = (const float*)d_in[12];
    const float* Wa3 = (const float*)d_in[13];
    const float* ba3 = (const float*)d_in[14];
    const float* Wc1 = (const float*)d_in[15];
    const float* bc1 = (const float*)d_in[16];
    const float* Wc2 = (const float*)d_in[17];
    const float* bc2 = (const float*)d_in[18];

    const int N = in_sizes[0] / NDIM;
    const int E = in_sizes[1];
    float* out = (float*)d_out;

    // workspace layout (wt first for 16B alignment)
    unsigned short* wt = (unsigned short*)d_ws;            // 6 * 32768 ushorts = 384 KB
    float* bufA = (float*)((char*)d_ws + 6 * 32768 * 2);   // N*128
    float* bufB = bufA + (size_t)N * NDIM;                 // N*128
    float* proj = bufB + (size_t)N * NDIM;                 // N*8
    int* cnt    = (int*)(proj + (size_t)N * 8);            // N
    int* offs   = cnt + N;                                 // N+1
    int* cursor = offs + N + 1;                            // N
    int* bsums  = cursor + N;                              // 128
    int* perm   = bsums + 128;                             // E

    const unsigned short* wt_m1  = wt;
    const unsigned short* wt_m2  = wt + 1 * 32768;
    const unsigned short* wt_m3  = wt + 2 * 32768;
    const unsigned short* wt_c1a = wt + 3 * 32768;
    const unsigned short* wt_c1b = wt + 4 * 32768;
    const unsigned short* wt_c2  = wt + 5 * 32768;

    hipMemsetAsync(cnt, 0, (size_t)N * sizeof(int), stream);

    k_cvt_w<<<dim3(64, 6), 256, 0, stream>>>(Wm1, Wm2, Wm3, Wc1, Wc1 + 128 * 128, Wc2, wt);
    k_proj<<<256, 256, 0, stream>>>(h, Wa1, Wa2, Wa3, proj, N);
    k_hist<<<(E + 255) / 256, 256, 0, stream>>>(dst, cnt, E);

    int nb = (N + 511) / 512;
    k_scan1<<<nb, 512, 0, stream>>>(cnt, offs, bsums, N);
    k_scan2<<<1, 128, 0, stream>>>(bsums, nb);
    k_scan3<<<nb, 512, 0, stream>>>(offs, bsums, cursor, N, E);

    k_edge<<<(E + 255) / 256, 256, 0, stream>>>(src, dst, cursor, perm, E);

    int gb = (N + 127) / 128;
    // 3-layer message MLP in node domain; layer 3 writes bf16 msg in-place over bufB
    k_mfma<<<gb, 512, 0, stream>>>(h,    nullptr, wt_m1, nullptr, bm1, bufA, N, 1, 0);
    k_mfma<<<gb, 512, 0, stream>>>(bufA, nullptr, wt_m2, nullptr, bm2, bufB, N, 1, 0);
    k_mfma<<<gb, 512, 0, stream>>>(bufB, nullptr, wt_m3, nullptr, bm3, bufB, N, 1, 1);
    unsigned short* msgb = (unsigned short*)bufB;

    // aggregation: one 16-lane group per node; hneigh -> bufA
    int nwaves = (N + 3) / 4;
    int nblk   = (nwaves + 3) / 4;     // 4 waves per 256-thread block
    k_aggr<<<nblk, 256, 0, stream>>>(msgb, proj, offs, perm, ba1, ba2, ba3, bufA, N);

    // out = relu(h@Wc1[:128] + hneigh@Wc1[128:] + bc1) @ Wc2 + bc2
    k_mfma<<<gb, 512, 0, stream>>>(h, bufA, wt_c1a, wt_c1b, bc1, bufB, N, 1, 0);
    k_mfma<<<gb, 512, 0, stream>>>(bufB, nullptr, wt_c2, nullptr, bc2, out, N, 0, 0);
}